// Round 13
// baseline (1234.479 us; speedup 1.0000x reference)
//
#include <hip/hip_runtime.h>
#include <math.h>

#define NB 8
#define NH 256
#define NW 256
#define NC 180
#define NE 6
#define HD 30
#define NL 256
#define NK 64
#define NWIN 2048

typedef __attribute__((ext_vector_type(8))) short bf16x8;
typedef __attribute__((ext_vector_type(4))) float f32x4;

union FU { bf16x8 f; unsigned u[4]; unsigned short s[8]; };

static __device__ __forceinline__ unsigned short f2bf(float x) {
    unsigned u = __float_as_uint(x);
    unsigned r = (u + 0x7FFFu + ((u >> 16) & 1u)) >> 16;
    return (unsigned short)r;
}
static __device__ __forceinline__ unsigned pk2(float a, float b) {
    return (unsigned)f2bf(a) | ((unsigned)f2bf(b) << 16);
}
// fragment load: elements {p[0..3], p[16..19]} — 8B-aligned rows
static __device__ __forceinline__ bf16x8 ld8(const unsigned short* p) {
    FU t;
    *(uint2*)&t.u[0] = *(const uint2*)p;
    *(uint2*)&t.u[2] = *(const uint2*)(p + 16);
    return t.f;
}
// same element order, 4B-aligned rows (stride-34 LDS)
static __device__ __forceinline__ bf16x8 ld8q(const unsigned short* p) {
    FU t;
    t.u[0] = *(const unsigned*)p;
    t.u[1] = *(const unsigned*)(p + 2);
    t.u[2] = *(const unsigned*)(p + 16);
    t.u[3] = *(const unsigned*)(p + 18);
    return t.f;
}
static __device__ __forceinline__ bf16x8 pack8(float4 a, float4 b) {
    FU t;
    t.u[0] = pk2(a.x, a.y); t.u[1] = pk2(a.z, a.w);
    t.u[2] = pk2(b.x, b.y); t.u[3] = pk2(b.z, b.w);
    return t.f;
}

// ---------------------------------------------------------------------------
// prep: Wqkv_t[h][n'<96][k<192] (n' = sec*32+r, n = sec*30+r; pads zero)
//       Wcomb_t[h][o<192][d<32] = (Wo[h] @ Wp^T)^T  (pads zero)
// ---------------------------------------------------------------------------
__global__ __launch_bounds__(256) void k_prep(
    const float* __restrict__ Wqkv, const float* __restrict__ Wo,
    const float* __restrict__ Wp,
    unsigned short* __restrict__ Wqkv_t, unsigned short* __restrict__ Wcomb_t)
{
    int i = blockIdx.x * 256 + threadIdx.x;
    if (i < NE * 96 * 192) {
        int h = i / (96 * 192), rm = i % (96 * 192), np = rm / 192, k = rm % 192;
        int sec = np >> 5, r = np & 31;
        float v = (r < 30 && k < NC) ? Wqkv[((long)h * NC + k) * 90 + sec * 30 + r] : 0.f;
        Wqkv_t[i] = f2bf(v);
    }
    if (i < NE * 192 * 32) {
        int h = i / (192 * 32), rm = i % (192 * 32), o = rm / 32, d = rm & 31;
        float acc = 0.f;
        if (o < NC && d < HD) {
            const float* wo = Wo + ((long)h * HD + d) * NC;
            const float* wp = Wp + (long)o * NC;
            for (int c = 0; c < NC; ++c) acc += wo[c] * wp[c];
        }
        Wcomb_t[i] = f2bf(acc);
    }
}

// ---------------------------------------------------------------------------
// Router: staging + logit + sigmoid phases VERBATIM from round 1 (those
// compiled float bits match the np reference's selection exactly — do not
// touch). Selection phase replaced by an exact bitonic sort on the sigmoid
// BITS: composite u64 key (bits<<32)|(0xFFFFFFFF - tok); sigmoid>0 so float
// bits are order-monotonic; tie lower-index-wins via low word; token 0 key=0
// sorts last. Sorted position == rank -> identical slots/vals as rank-count.
// ---------------------------------------------------------------------------
__global__ __launch_bounds__(256) void k_router_topk(
    const float* __restrict__ x, const float* __restrict__ Wr,
    int* __restrict__ idx_g, float* __restrict__ vals_g)
{
    __shared__ float wr_s[NE * NC];
    __shared__ __align__(16) float xs[32 * 181];   // overlaid by keys after logits
    __shared__ float lg[NE * NL];

    const int w   = blockIdx.x;
    const int tid = threadIdx.x;
    const int b = w >> 8, hb = (w >> 4) & 15, wb = w & 15;
    const long win_base = (((long)b * NH + hb * 16) * NW + wb * 16) * NC;

    for (int f = tid; f < NE * NC; f += 256) wr_s[f] = Wr[f];
    __syncthreads();

    for (int tile = 0; tile < 8; ++tile) {
        for (int f = tid; f < 32 * NC; f += 256) {
            int tl = f / NC, ch = f % NC;
            int tok = tile * 32 + tl;
            int r = tok >> 4, cl = tok & 15;
            xs[tl * 181 + ch] = x[win_base + ((long)r * NW + cl) * NC + ch];
        }
        __syncthreads();
        if (tid < 192) {
            int tl = tid & 31, e = tid >> 5;
            float acc = 0.f;
            for (int c = 0; c < NC; ++c) acc += xs[tl * 181 + c] * wr_s[e * NC + c];
            lg[e * NL + tile * 32 + tl] = 1.0f / (1.0f + expf(-acc));
        }
        __syncthreads();
    }

    // ---- exact top-63 via bitonic sort of composite keys (bits identical) --
    unsigned long long* keys = (unsigned long long*)xs;  // xs dead; barriers pin
    #pragma unroll
    for (int e = 0; e < NE; ++e) {
        unsigned kb = __float_as_uint(lg[e * NL + tid]);
        unsigned long long comp =
            ((unsigned long long)kb << 32) | (unsigned)(0xFFFFFFFFu - tid);
        if (tid == 0) comp = 0ull;   // token 0 excluded from ranked list
        keys[e * NL + tid] = comp;
    }
    __syncthreads();

    for (int k = 2; k <= 256; k <<= 1) {
        for (int j = k >> 1; j > 0; j >>= 1) {
            const int i = tid, ixj = i ^ j;
            if (ixj > i) {
                const bool up = ((i & k) == 0);
                #pragma unroll
                for (int e = 0; e < NE; ++e) {
                    unsigned long long a  = keys[e * NL + i];
                    unsigned long long bv = keys[e * NL + ixj];
                    bool sw = up ? (a < bv) : (a > bv);   // descending sort
                    if (sw) { keys[e * NL + i] = bv; keys[e * NL + ixj] = a; }
                }
            }
            __syncthreads();
        }
    }

    if (tid < NK - 1) {   // sorted position == rank; slots 1..63
        #pragma unroll
        for (int e = 0; e < NE; ++e) {
            unsigned long long kk = keys[e * NL + tid];
            int t = (int)(0xFFFFFFFFu - (unsigned)kk);
            idx_g[(w * NE + e) * NK + 1 + tid]  = t;
            vals_g[(w * NE + e) * NK + 1 + tid] = __uint_as_float((unsigned)(kk >> 32));
        }
    }
    if (tid == 0) {
        #pragma unroll
        for (int e = 0; e < NE; ++e) {
            idx_g[(w * NE + e) * NK]  = 0;
            vals_g[(w * NE + e) * NK] = lg[e * NL];
        }
    }
}

// ---------------------------------------------------------------------------
// k_attn: one WAVE per (window, head), w-major. UNCHANGED from round 12.
//   at_g[(h*2048 + w)*64 + slot][32] bf16  (cols 30,31 zero-pad)
// ---------------------------------------------------------------------------
__global__ __launch_bounds__(256, 3) void k_attn(
    const float* __restrict__ x,
    const unsigned short* __restrict__ Wqkv_t,
    const int* __restrict__ idx_g, const float* __restrict__ vals_g,
    unsigned short* __restrict__ at_g)
{
    __shared__ char sm[34816];
    const int tid = threadIdx.x;
    const int wv = tid >> 6;
    const int ln = tid & 63;
    const int lr = ln & 15;
    const int lg = ln >> 4;

    const int id = blockIdx.x * 4 + wv;      // w-major: id = w*6 + h
    const int w = id / 6;
    const int h = id % 6;
    const int b = w >> 8, hb = (w >> 4) & 15, wb = w & 15;
    const long win_base = (((long)b * NH + hb * 16) * NW + wb * 16) * NC;

    unsigned short* q_s = (unsigned short*)(sm + wv * 8704);
    unsigned short* k_s = q_s + 2176;

    int tokr[4];
    #pragma unroll
    for (int t = 0; t < 4; ++t)
        tokr[t] = idx_g[((long)w * NE + h) * NK + 16 * t + lr];

    // --- QKV = gather(x) @ Wqkv_t : M=64, N=96, K=192 ---
    f32x4 acc[6][4];
    #pragma unroll
    for (int nt = 0; nt < 6; ++nt)
        #pragma unroll
        for (int mt = 0; mt < 4; ++mt) acc[nt][mt] = (f32x4){0.f, 0.f, 0.f, 0.f};

    const unsigned short* bb = Wqkv_t + ((long)h * 96 + lr) * 192 + 4 * lg;
    #pragma unroll
    for (int kt = 0; kt < 6; ++kt) {
        bf16x8 Amt[4];
        #pragma unroll
        for (int mt = 0; mt < 4; ++mt) {
            const float* xr = x + win_base +
                ((long)(tokr[mt] >> 4) * NW + (tokr[mt] & 15)) * NC;
            if (kt < 5) {
                float4 a  = *(const float4*)(xr + 4 * lg + 32 * kt);
                float4 b2 = *(const float4*)(xr + 4 * lg + 32 * kt + 16);
                Amt[mt] = pack8(a, b2);
            } else {
                float4 a  = *(const float4*)(xr + 4 * lg + 160);
                float4 b2 = make_float4(0.f, 0.f, 0.f, 0.f);
                if (lg == 0) b2 = *(const float4*)(xr + 176);
                Amt[mt] = pack8(a, b2);
            }
        }
        #pragma unroll
        for (int nt = 0; nt < 6; ++nt) {
            bf16x8 B = ld8(bb + nt * (16 * 192) + kt * 32);
            #pragma unroll
            for (int mt = 0; mt < 4; ++mt)
                acc[nt][mt] = __builtin_amdgcn_mfma_f32_16x16x32_bf16(Amt[mt], B, acc[nt][mt], 0, 0, 0);
        }
    }

    // --- write Q/K (nt 0..3) to LDS transpose buffers; V (nt 4,5) in regs ---
    #pragma unroll
    for (int nt = 0; nt < 4; ++nt) {
        unsigned short* dst = (nt < 2 ? q_s : k_s) + 16 * (nt & 1) + lr;
        #pragma unroll
        for (int mt = 0; mt < 4; ++mt) {
            int row = 16 * mt + 4 * lg;
            dst[(row + 0) * 34] = f2bf(acc[nt][mt][0]);
            dst[(row + 1) * 34] = f2bf(acc[nt][mt][1]);
            dst[(row + 2) * 34] = f2bf(acc[nt][mt][2]);
            dst[(row + 3) * 34] = f2bf(acc[nt][mt][3]);
        }
    }
    unsigned V32[4][2][2];
    #pragma unroll
    for (int j = 0; j < 2; ++j)
        #pragma unroll
        for (int mt = 0; mt < 4; ++mt) {
            V32[mt][j][0] = pk2(acc[4 + j][mt][0], acc[4 + j][mt][1]);
            V32[mt][j][1] = pk2(acc[4 + j][mt][2], acc[4 + j][mt][3]);
        }

    // TBAA pin: u16 ds_writes above vs u32 ds_reads below (round-7 lesson)
    __syncthreads();

    // --- scores^T = mfma(K, Q) ---
    f32x4 s[4][4];
    {
        bf16x8 Bq[4];
        #pragma unroll
        for (int nt = 0; nt < 4; ++nt)
            Bq[nt] = ld8q(q_s + (16 * nt + lr) * 34 + 4 * lg);
        #pragma unroll
        for (int amt = 0; amt < 4; ++amt) {
            bf16x8 Ak = ld8q(k_s + (16 * amt + lr) * 34 + 4 * lg);
            #pragma unroll
            for (int nt = 0; nt < 4; ++nt)
                s[amt][nt] = __builtin_amdgcn_mfma_f32_16x16x32_bf16(
                    Ak, Bq[nt], (f32x4){0.f, 0.f, 0.f, 0.f}, 0, 0, 0);
        }
    }

    // --- in-register softmax + gate ---
    float gsc[4];
    #pragma unroll
    for (int nt = 0; nt < 4; ++nt) {
        float mx = -1e30f;
        #pragma unroll
        for (int amt = 0; amt < 4; ++amt)
            #pragma unroll
            for (int r = 0; r < 4; ++r) mx = fmaxf(mx, s[amt][nt][r]);
        mx = fmaxf(mx, __shfl_xor(mx, 16));
        mx = fmaxf(mx, __shfl_xor(mx, 32));
        float sum = 0.f;
        #pragma unroll
        for (int amt = 0; amt < 4; ++amt)
            #pragma unroll
            for (int r = 0; r < 4; ++r) {
                float p = __expf((s[amt][nt][r] - mx) * 0.18257418583505536f);
                s[amt][nt][r] = p;
                sum += p;
            }
        sum += __shfl_xor(sum, 16);
        sum += __shfl_xor(sum, 32);
        gsc[nt] = vals_g[((long)w * NE + h) * NK + 16 * nt + lr] / sum;
    }

    // --- attn^T = mfma(V^T, P^T); pack as B-fragments ---
    bf16x8 Av[2][2];
    #pragma unroll
    for (int amt = 0; amt < 2; ++amt)
        #pragma unroll
        for (int kt = 0; kt < 2; ++kt) {
            FU t;
            t.u[0] = V32[2 * kt][amt][0];
            t.u[1] = V32[2 * kt][amt][1];
            t.u[2] = V32[2 * kt + 1][amt][0];
            t.u[3] = V32[2 * kt + 1][amt][1];
            Av[amt][kt] = t.f;
        }
    #pragma unroll
    for (int nt = 0; nt < 4; ++nt) {
        bf16x8 Pb[2];
        float g = gsc[nt];
        #pragma unroll
        for (int kt = 0; kt < 2; ++kt) {
            FU t;
            t.u[0] = pk2(s[2 * kt][nt][0] * g, s[2 * kt][nt][1] * g);
            t.u[1] = pk2(s[2 * kt][nt][2] * g, s[2 * kt][nt][3] * g);
            t.u[2] = pk2(s[2 * kt + 1][nt][0] * g, s[2 * kt + 1][nt][1] * g);
            t.u[3] = pk2(s[2 * kt + 1][nt][2] * g, s[2 * kt + 1][nt][3] * g);
            Pb[kt] = t.f;
        }
        f32x4 a0 = (f32x4){0.f, 0.f, 0.f, 0.f};
        a0 = __builtin_amdgcn_mfma_f32_16x16x32_bf16(Av[0][0], Pb[0], a0, 0, 0, 0);
        a0 = __builtin_amdgcn_mfma_f32_16x16x32_bf16(Av[0][1], Pb[1], a0, 0, 0, 0);
        f32x4 a1 = (f32x4){0.f, 0.f, 0.f, 0.f};
        a1 = __builtin_amdgcn_mfma_f32_16x16x32_bf16(Av[1][0], Pb[0], a1, 0, 0, 0);
        a1 = __builtin_amdgcn_mfma_f32_16x16x32_bf16(Av[1][1], Pb[1], a1, 0, 0, 0);
        unsigned short* row = at_g + (((long)h * NWIN + w) * 64 + 16 * nt + lr) * 32;
        *(uint2*)(row + 4 * lg)      = make_uint2(pk2(a0[0], a0[1]), pk2(a0[2], a0[3]));
        *(uint2*)(row + 16 + 4 * lg) = make_uint2(pk2(a1[0], a1[1]), pk2(a1[2], a1[3]));
    }
}

// ---------------------------------------------------------------------------
// k_scatter: one block per (channel-pass p, window w). ALL 6 waves active:
// wave-group hg = wv/3 handles heads 3hg..3hg+2; cross-group (tok,col)
// collisions resolved by LDS atomicAdd (ds_add_f32, proven round 10).
// ---------------------------------------------------------------------------
__global__ __launch_bounds__(384) void k_scatter(
    const unsigned short* __restrict__ at_g,
    const unsigned short* __restrict__ Wcomb_t,
    const float* __restrict__ bp,
    const int* __restrict__ idx_g,
    float* __restrict__ out)
{
    __shared__ float outf[256 * 49];
    __shared__ unsigned char idx_s[NE * NK];

    const int p = blockIdx.x;
    const int w = blockIdx.y;
    const int tid = threadIdx.x;
    const int b = w >> 8, hb = (w >> 4) & 15, wb = w & 15;

    const int wv = tid >> 6;
    const int ln = tid & 63;
    const int lr = ln & 15;
    const int lg = ln >> 4;

    if (tid < NE * NK) idx_s[tid] = (unsigned char)idx_g[(long)w * NE * NK + tid];
    for (int f = tid; f < 256 * 49; f += 384) outf[f] = 0.f;
    __syncthreads();

    {
        const int wcol = wv % 3;
        const int hg = wv / 3;
        #pragma unroll 1
        for (int hh = 0; hh < 3; ++hh) {
            const int h = hg * 3 + hh;
            bf16x8 Aw = ld8(Wcomb_t + ((long)h * 192 + p * 48 + 16 * wcol + lr) * 32 + 4 * lg);
            #pragma unroll
            for (int nt = 0; nt < 4; ++nt) {
                bf16x8 Bt = ld8(at_g + (((long)h * NWIN + w) * 64 + 16 * nt + lr) * 32 + 4 * lg);
                f32x4 acc = __builtin_amdgcn_mfma_f32_16x16x32_bf16(
                    Aw, Bt, (f32x4){0.f, 0.f, 0.f, 0.f}, 0, 0, 0);
                int tok = idx_s[h * NK + 16 * nt + lr];
                float* dst = outf + tok * 49 + 16 * wcol + 4 * lg;
                atomicAdd(&dst[0], acc[0]);
                atomicAdd(&dst[1], acc[1]);
                atomicAdd(&dst[2], acc[2]);
                atomicAdd(&dst[3], acc[3]);
            }
        }
    }
    __syncthreads();

    const int cl2 = (p == 3) ? 18 : 24;  // float2 cols this pass (c<180)
    for (int f = tid; f < 256 * cl2; f += 384) {
        int t = f / cl2, j = f % cl2;
        int c = 48 * p + 2 * j;
        float2 o;
        o.x = outf[t * 49 + 2 * j]     + bp[c];
        o.y = outf[t * 49 + 2 * j + 1] + bp[c + 1];
        long obase = (((long)b * NH + hb * 16 + (t >> 4)) * NW + wb * 16 + (t & 15)) * NC + c;
        *(float2*)(out + obase) = o;
    }
}

// ---------------------------------------------------------------------------
extern "C" void kernel_launch(void* const* d_in, const int* in_sizes, int n_in,
                              void* d_out, int out_size, void* d_ws, size_t ws_size,
                              hipStream_t stream) {
    const float* x    = (const float*)d_in[0];
    const float* Wr   = (const float*)d_in[1];
    const float* Wqkv = (const float*)d_in[2];
    const float* Wo   = (const float*)d_in[3];
    const float* Wp   = (const float*)d_in[4];
    const float* bp   = (const float*)d_in[5];
    float* out = (float*)d_out;

    char* ws = (char*)d_ws;
    unsigned short* Wqkv_t  = (unsigned short*)ws;                  // 221184 B
    unsigned short* Wcomb_t = (unsigned short*)(ws + 221184);       // 73728 B
    int*   idx_g  = (int*)(ws + 294912);                            // 3 MB
    float* vals_g = (float*)(ws + 294912 + (size_t)NWIN * NE * NK * 4);
    unsigned short* at_g = (unsigned short*)(ws + 294912 + 2 * (size_t)NWIN * NE * NK * 4);  // 48 MB

    k_prep<<<432, 256, 0, stream>>>(Wqkv, Wo, Wp, Wqkv_t, Wcomb_t);
    k_router_topk<<<NWIN, 256, 0, stream>>>(x, Wr, idx_g, vals_g);
    k_attn<<<3072, 256, 0, stream>>>(x, Wqkv_t, idx_g, vals_g, at_g);
    k_scatter<<<dim3(4, NWIN), 384, 0, stream>>>(at_g, Wcomb_t, bp, idx_g, out);
}

// Round 14
// 650.434 us; speedup vs baseline: 1.8979x; 1.8979x over previous
//
#include <hip/hip_runtime.h>
#include <math.h>

#define NB 8
#define NH 256
#define NW 256
#define NC 180
#define NE 6
#define HD 30
#define NL 256
#define NK 64
#define NWIN 2048

typedef __attribute__((ext_vector_type(8))) short bf16x8;
typedef __attribute__((ext_vector_type(4))) float f32x4;

union FU { bf16x8 f; unsigned u[4]; unsigned short s[8]; };

static __device__ __forceinline__ unsigned short f2bf(float x) {
    unsigned u = __float_as_uint(x);
    unsigned r = (u + 0x7FFFu + ((u >> 16) & 1u)) >> 16;
    return (unsigned short)r;
}
static __device__ __forceinline__ unsigned pk2(float a, float b) {
    return (unsigned)f2bf(a) | ((unsigned)f2bf(b) << 16);
}
// fragment load: elements {p[0..3], p[16..19]} — 8B-aligned rows
static __device__ __forceinline__ bf16x8 ld8(const unsigned short* p) {
    FU t;
    *(uint2*)&t.u[0] = *(const uint2*)p;
    *(uint2*)&t.u[2] = *(const uint2*)(p + 16);
    return t.f;
}
// same element order, 4B-aligned rows (stride-34 LDS)
static __device__ __forceinline__ bf16x8 ld8q(const unsigned short* p) {
    FU t;
    t.u[0] = *(const unsigned*)p;
    t.u[1] = *(const unsigned*)(p + 2);
    t.u[2] = *(const unsigned*)(p + 16);
    t.u[3] = *(const unsigned*)(p + 18);
    return t.f;
}
static __device__ __forceinline__ bf16x8 pack8(float4 a, float4 b) {
    FU t;
    t.u[0] = pk2(a.x, a.y); t.u[1] = pk2(a.z, a.w);
    t.u[2] = pk2(b.x, b.y); t.u[3] = pk2(b.z, b.w);
    return t.f;
}

// ---------------------------------------------------------------------------
// prep: Wqkv_t[h][n'<96][k<192] (n' = sec*32+r, n = sec*30+r; pads zero)
//       Wcomb_t[h][o<192][d<32] = (Wo[h] @ Wp^T)^T  (pads zero)
// ---------------------------------------------------------------------------
__global__ __launch_bounds__(256) void k_prep(
    const float* __restrict__ Wqkv, const float* __restrict__ Wo,
    const float* __restrict__ Wp,
    unsigned short* __restrict__ Wqkv_t, unsigned short* __restrict__ Wcomb_t)
{
    int i = blockIdx.x * 256 + threadIdx.x;
    if (i < NE * 96 * 192) {
        int h = i / (96 * 192), rm = i % (96 * 192), np = rm / 192, k = rm % 192;
        int sec = np >> 5, r = np & 31;
        float v = (r < 30 && k < NC) ? Wqkv[((long)h * NC + k) * 90 + sec * 30 + r] : 0.f;
        Wqkv_t[i] = f2bf(v);
    }
    if (i < NE * 192 * 32) {
        int h = i / (192 * 32), rm = i % (192 * 32), o = rm / 32, d = rm & 31;
        float acc = 0.f;
        if (o < NC && d < HD) {
            const float* wo = Wo + ((long)h * HD + d) * NC;
            const float* wp = Wp + (long)o * NC;
            for (int c = 0; c < NC; ++c) acc += wo[c] * wp[c];
        }
        Wcomb_t[i] = f2bf(acc);
    }
}

// ---------------------------------------------------------------------------
// Router: staging + logit + sigmoid phases VERBATIM from round 1 (those
// compiled float bits match the np reference's selection exactly — do not
// touch). Selection: exact bitonic sort on sigmoid bits (round-13-proven,
// bit-identical selection, ~4x fewer instructions than rank-count).
// ---------------------------------------------------------------------------
__global__ __launch_bounds__(256) void k_router_topk(
    const float* __restrict__ x, const float* __restrict__ Wr,
    int* __restrict__ idx_g, float* __restrict__ vals_g)
{
    __shared__ float wr_s[NE * NC];
    __shared__ __align__(16) float xs[32 * 181];   // overlaid by keys after logits
    __shared__ float lg[NE * NL];

    const int w   = blockIdx.x;
    const int tid = threadIdx.x;
    const int b = w >> 8, hb = (w >> 4) & 15, wb = w & 15;
    const long win_base = (((long)b * NH + hb * 16) * NW + wb * 16) * NC;

    for (int f = tid; f < NE * NC; f += 256) wr_s[f] = Wr[f];
    __syncthreads();

    for (int tile = 0; tile < 8; ++tile) {
        for (int f = tid; f < 32 * NC; f += 256) {
            int tl = f / NC, ch = f % NC;
            int tok = tile * 32 + tl;
            int r = tok >> 4, cl = tok & 15;
            xs[tl * 181 + ch] = x[win_base + ((long)r * NW + cl) * NC + ch];
        }
        __syncthreads();
        if (tid < 192) {
            int tl = tid & 31, e = tid >> 5;
            float acc = 0.f;
            for (int c = 0; c < NC; ++c) acc += xs[tl * 181 + c] * wr_s[e * NC + c];
            lg[e * NL + tile * 32 + tl] = 1.0f / (1.0f + expf(-acc));
        }
        __syncthreads();
    }

    // ---- exact top-63 via bitonic sort of composite keys (bits identical) --
    unsigned long long* keys = (unsigned long long*)xs;  // xs dead; barriers pin
    #pragma unroll
    for (int e = 0; e < NE; ++e) {
        unsigned kb = __float_as_uint(lg[e * NL + tid]);
        unsigned long long comp =
            ((unsigned long long)kb << 32) | (unsigned)(0xFFFFFFFFu - tid);
        if (tid == 0) comp = 0ull;   // token 0 excluded from ranked list
        keys[e * NL + tid] = comp;
    }
    __syncthreads();

    for (int k = 2; k <= 256; k <<= 1) {
        for (int j = k >> 1; j > 0; j >>= 1) {
            const int i = tid, ixj = i ^ j;
            if (ixj > i) {
                const bool up = ((i & k) == 0);
                #pragma unroll
                for (int e = 0; e < NE; ++e) {
                    unsigned long long a  = keys[e * NL + i];
                    unsigned long long bv = keys[e * NL + ixj];
                    bool sw = up ? (a < bv) : (a > bv);   // descending sort
                    if (sw) { keys[e * NL + i] = bv; keys[e * NL + ixj] = a; }
                }
            }
            __syncthreads();
        }
    }

    if (tid < NK - 1) {   // sorted position == rank; slots 1..63
        #pragma unroll
        for (int e = 0; e < NE; ++e) {
            unsigned long long kk = keys[e * NL + tid];
            int t = (int)(0xFFFFFFFFu - (unsigned)kk);
            idx_g[(w * NE + e) * NK + 1 + tid]  = t;
            vals_g[(w * NE + e) * NK + 1 + tid] = __uint_as_float((unsigned)(kk >> 32));
        }
    }
    if (tid == 0) {
        #pragma unroll
        for (int e = 0; e < NE; ++e) {
            idx_g[(w * NE + e) * NK]  = 0;
            vals_g[(w * NE + e) * NK] = lg[e * NL];
        }
    }
}

// ---------------------------------------------------------------------------
// k_attn: one WAVE per (window, head), w-major. UNCHANGED from round 12.
//   at_g[(h*2048 + w)*64 + slot][32] bf16  (cols 30,31 zero-pad)
// ---------------------------------------------------------------------------
__global__ __launch_bounds__(256, 3) void k_attn(
    const float* __restrict__ x,
    const unsigned short* __restrict__ Wqkv_t,
    const int* __restrict__ idx_g, const float* __restrict__ vals_g,
    unsigned short* __restrict__ at_g)
{
    __shared__ char sm[34816];
    const int tid = threadIdx.x;
    const int wv = tid >> 6;
    const int ln = tid & 63;
    const int lr = ln & 15;
    const int lg = ln >> 4;

    const int id = blockIdx.x * 4 + wv;      // w-major: id = w*6 + h
    const int w = id / 6;
    const int h = id % 6;
    const int b = w >> 8, hb = (w >> 4) & 15, wb = w & 15;
    const long win_base = (((long)b * NH + hb * 16) * NW + wb * 16) * NC;

    unsigned short* q_s = (unsigned short*)(sm + wv * 8704);
    unsigned short* k_s = q_s + 2176;

    int tokr[4];
    #pragma unroll
    for (int t = 0; t < 4; ++t)
        tokr[t] = idx_g[((long)w * NE + h) * NK + 16 * t + lr];

    // --- QKV = gather(x) @ Wqkv_t : M=64, N=96, K=192 ---
    f32x4 acc[6][4];
    #pragma unroll
    for (int nt = 0; nt < 6; ++nt)
        #pragma unroll
        for (int mt = 0; mt < 4; ++mt) acc[nt][mt] = (f32x4){0.f, 0.f, 0.f, 0.f};

    const unsigned short* bb = Wqkv_t + ((long)h * 96 + lr) * 192 + 4 * lg;
    #pragma unroll
    for (int kt = 0; kt < 6; ++kt) {
        bf16x8 Amt[4];
        #pragma unroll
        for (int mt = 0; mt < 4; ++mt) {
            const float* xr = x + win_base +
                ((long)(tokr[mt] >> 4) * NW + (tokr[mt] & 15)) * NC;
            if (kt < 5) {
                float4 a  = *(const float4*)(xr + 4 * lg + 32 * kt);
                float4 b2 = *(const float4*)(xr + 4 * lg + 32 * kt + 16);
                Amt[mt] = pack8(a, b2);
            } else {
                float4 a  = *(const float4*)(xr + 4 * lg + 160);
                float4 b2 = make_float4(0.f, 0.f, 0.f, 0.f);
                if (lg == 0) b2 = *(const float4*)(xr + 176);
                Amt[mt] = pack8(a, b2);
            }
        }
        #pragma unroll
        for (int nt = 0; nt < 6; ++nt) {
            bf16x8 B = ld8(bb + nt * (16 * 192) + kt * 32);
            #pragma unroll
            for (int mt = 0; mt < 4; ++mt)
                acc[nt][mt] = __builtin_amdgcn_mfma_f32_16x16x32_bf16(Amt[mt], B, acc[nt][mt], 0, 0, 0);
        }
    }

    // --- write Q/K (nt 0..3) to LDS transpose buffers; V (nt 4,5) in regs ---
    #pragma unroll
    for (int nt = 0; nt < 4; ++nt) {
        unsigned short* dst = (nt < 2 ? q_s : k_s) + 16 * (nt & 1) + lr;
        #pragma unroll
        for (int mt = 0; mt < 4; ++mt) {
            int row = 16 * mt + 4 * lg;
            dst[(row + 0) * 34] = f2bf(acc[nt][mt][0]);
            dst[(row + 1) * 34] = f2bf(acc[nt][mt][1]);
            dst[(row + 2) * 34] = f2bf(acc[nt][mt][2]);
            dst[(row + 3) * 34] = f2bf(acc[nt][mt][3]);
        }
    }
    unsigned V32[4][2][2];
    #pragma unroll
    for (int j = 0; j < 2; ++j)
        #pragma unroll
        for (int mt = 0; mt < 4; ++mt) {
            V32[mt][j][0] = pk2(acc[4 + j][mt][0], acc[4 + j][mt][1]);
            V32[mt][j][1] = pk2(acc[4 + j][mt][2], acc[4 + j][mt][3]);
        }

    // TBAA pin: u16 ds_writes above vs u32 ds_reads below (round-7 lesson)
    __syncthreads();

    // --- scores^T = mfma(K, Q) ---
    f32x4 s[4][4];
    {
        bf16x8 Bq[4];
        #pragma unroll
        for (int nt = 0; nt < 4; ++nt)
            Bq[nt] = ld8q(q_s + (16 * nt + lr) * 34 + 4 * lg);
        #pragma unroll
        for (int amt = 0; amt < 4; ++amt) {
            bf16x8 Ak = ld8q(k_s + (16 * amt + lr) * 34 + 4 * lg);
            #pragma unroll
            for (int nt = 0; nt < 4; ++nt)
                s[amt][nt] = __builtin_amdgcn_mfma_f32_16x16x32_bf16(
                    Ak, Bq[nt], (f32x4){0.f, 0.f, 0.f, 0.f}, 0, 0, 0);
        }
    }

    // --- in-register softmax + gate ---
    float gsc[4];
    #pragma unroll
    for (int nt = 0; nt < 4; ++nt) {
        float mx = -1e30f;
        #pragma unroll
        for (int amt = 0; amt < 4; ++amt)
            #pragma unroll
            for (int r = 0; r < 4; ++r) mx = fmaxf(mx, s[amt][nt][r]);
        mx = fmaxf(mx, __shfl_xor(mx, 16));
        mx = fmaxf(mx, __shfl_xor(mx, 32));
        float sum = 0.f;
        #pragma unroll
        for (int amt = 0; amt < 4; ++amt)
            #pragma unroll
            for (int r = 0; r < 4; ++r) {
                float p = __expf((s[amt][nt][r] - mx) * 0.18257418583505536f);
                s[amt][nt][r] = p;
                sum += p;
            }
        sum += __shfl_xor(sum, 16);
        sum += __shfl_xor(sum, 32);
        gsc[nt] = vals_g[((long)w * NE + h) * NK + 16 * nt + lr] / sum;
    }

    // --- attn^T = mfma(V^T, P^T); pack as B-fragments ---
    bf16x8 Av[2][2];
    #pragma unroll
    for (int amt = 0; amt < 2; ++amt)
        #pragma unroll
        for (int kt = 0; kt < 2; ++kt) {
            FU t;
            t.u[0] = V32[2 * kt][amt][0];
            t.u[1] = V32[2 * kt][amt][1];
            t.u[2] = V32[2 * kt + 1][amt][0];
            t.u[3] = V32[2 * kt + 1][amt][1];
            Av[amt][kt] = t.f;
        }
    #pragma unroll
    for (int nt = 0; nt < 4; ++nt) {
        bf16x8 Pb[2];
        float g = gsc[nt];
        #pragma unroll
        for (int kt = 0; kt < 2; ++kt) {
            FU t;
            t.u[0] = pk2(s[2 * kt][nt][0] * g, s[2 * kt][nt][1] * g);
            t.u[1] = pk2(s[2 * kt][nt][2] * g, s[2 * kt][nt][3] * g);
            t.u[2] = pk2(s[2 * kt + 1][nt][0] * g, s[2 * kt + 1][nt][1] * g);
            t.u[3] = pk2(s[2 * kt + 1][nt][2] * g, s[2 * kt + 1][nt][3] * g);
            Pb[kt] = t.f;
        }
        f32x4 a0 = (f32x4){0.f, 0.f, 0.f, 0.f};
        a0 = __builtin_amdgcn_mfma_f32_16x16x32_bf16(Av[0][0], Pb[0], a0, 0, 0, 0);
        a0 = __builtin_amdgcn_mfma_f32_16x16x32_bf16(Av[0][1], Pb[1], a0, 0, 0, 0);
        f32x4 a1 = (f32x4){0.f, 0.f, 0.f, 0.f};
        a1 = __builtin_amdgcn_mfma_f32_16x16x32_bf16(Av[1][0], Pb[0], a1, 0, 0, 0);
        a1 = __builtin_amdgcn_mfma_f32_16x16x32_bf16(Av[1][1], Pb[1], a1, 0, 0, 0);
        unsigned short* row = at_g + (((long)h * NWIN + w) * 64 + 16 * nt + lr) * 32;
        *(uint2*)(row + 4 * lg)      = make_uint2(pk2(a0[0], a0[1]), pk2(a0[2], a0[3]));
        *(uint2*)(row + 16 + 4 * lg) = make_uint2(pk2(a1[0], a1[1]), pk2(a1[2], a1[3]));
    }
}

// ---------------------------------------------------------------------------
// k_scatter: one block per (channel-pass p, window w). ALL 6 waves active,
// NO atomics (round-13: ds_add_f32 was ~10x slower than plain RMW):
//   wave = (nt-half, wcol). Within one head, all 64 selected tokens are
//   distinct -> nt-blocks are row-disjoint; wcol slices are col-disjoint.
//   A __syncthreads() after each head pins all waves to the same h interval,
//   so cross-head (tok,col) collisions are temporally separated.
// ---------------------------------------------------------------------------
__global__ __launch_bounds__(384) void k_scatter(
    const unsigned short* __restrict__ at_g,
    const unsigned short* __restrict__ Wcomb_t,
    const float* __restrict__ bp,
    const int* __restrict__ idx_g,
    float* __restrict__ out)
{
    __shared__ float outf[256 * 49];
    __shared__ unsigned char idx_s[NE * NK];

    const int p = blockIdx.x;
    const int w = blockIdx.y;
    const int tid = threadIdx.x;
    const int b = w >> 8, hb = (w >> 4) & 15, wb = w & 15;

    const int wv = tid >> 6;
    const int ln = tid & 63;
    const int lr = ln & 15;
    const int lg = ln >> 4;

    if (tid < NE * NK) idx_s[tid] = (unsigned char)idx_g[(long)w * NE * NK + tid];
    for (int f = tid; f < 256 * 49; f += 384) outf[f] = 0.f;
    __syncthreads();

    const int wcol = wv % 3;
    const int nth  = wv / 3;            // 0 or 1: nt-blocks {0,1} or {2,3}
    #pragma unroll 1
    for (int h = 0; h < NE; ++h) {
        bf16x8 Aw = ld8(Wcomb_t + ((long)h * 192 + p * 48 + 16 * wcol + lr) * 32 + 4 * lg);
        #pragma unroll
        for (int t = 0; t < 2; ++t) {
            const int nt = 2 * nth + t;
            bf16x8 Bt = ld8(at_g + (((long)h * NWIN + w) * 64 + 16 * nt + lr) * 32 + 4 * lg);
            f32x4 acc = __builtin_amdgcn_mfma_f32_16x16x32_bf16(
                Aw, Bt, (f32x4){0.f, 0.f, 0.f, 0.f}, 0, 0, 0);
            int tok = idx_s[h * NK + 16 * nt + lr];
            // same h: toks distinct across nt and lanes -> rows disjoint;
            // wcol -> cols disjoint. Plain RMW is race-free in this interval.
            float* dst = outf + tok * 49 + 16 * wcol + 4 * lg;
            dst[0] += acc[0];
            dst[1] += acc[1];
            dst[2] += acc[2];
            dst[3] += acc[3];
        }
        __syncthreads();   // separate head intervals (cross-head tok clashes)
    }

    const int cl2 = (p == 3) ? 18 : 24;  // float2 cols this pass (c<180)
    for (int f = tid; f < 256 * cl2; f += 384) {
        int t = f / cl2, j = f % cl2;
        int c = 48 * p + 2 * j;
        float2 o;
        o.x = outf[t * 49 + 2 * j]     + bp[c];
        o.y = outf[t * 49 + 2 * j + 1] + bp[c + 1];
        long obase = (((long)b * NH + hb * 16 + (t >> 4)) * NW + wb * 16 + (t & 15)) * NC + c;
        *(float2*)(out + obase) = o;
    }
}

// ---------------------------------------------------------------------------
extern "C" void kernel_launch(void* const* d_in, const int* in_sizes, int n_in,
                              void* d_out, int out_size, void* d_ws, size_t ws_size,
                              hipStream_t stream) {
    const float* x    = (const float*)d_in[0];
    const float* Wr   = (const float*)d_in[1];
    const float* Wqkv = (const float*)d_in[2];
    const float* Wo   = (const float*)d_in[3];
    const float* Wp   = (const float*)d_in[4];
    const float* bp   = (const float*)d_in[5];
    float* out = (float*)d_out;

    char* ws = (char*)d_ws;
    unsigned short* Wqkv_t  = (unsigned short*)ws;                  // 221184 B
    unsigned short* Wcomb_t = (unsigned short*)(ws + 221184);       // 73728 B
    int*   idx_g  = (int*)(ws + 294912);                            // 3 MB
    float* vals_g = (float*)(ws + 294912 + (size_t)NWIN * NE * NK * 4);
    unsigned short* at_g = (unsigned short*)(ws + 294912 + 2 * (size_t)NWIN * NE * NK * 4);  // 48 MB

    k_prep<<<432, 256, 0, stream>>>(Wqkv, Wo, Wp, Wqkv_t, Wcomb_t);
    k_router_topk<<<NWIN, 256, 0, stream>>>(x, Wr, idx_g, vals_g);
    k_attn<<<3072, 256, 0, stream>>>(x, Wqkv_t, idx_g, vals_g, at_g);
    k_scatter<<<dim3(4, NWIN), 384, 0, stream>>>(at_g, Wcomb_t, bp, idx_g, out);
}